// Round 15
// baseline (410.792 us; speedup 1.0000x reference)
//
#include <hip/hip_runtime.h>
#include <hip/hip_bf16.h>

// Hetero-SAGE: LDS-histogram CSR build (zero global atomics) + deep-ILP wide-lane
// gathers + all-bf16-MFMA GEMMs with folded classifier; layer-2 agg fused into the
// MFMA GEMM (means aggregated straight into swizzled LDS, no aggb round-trip).
#define NUV 100000
#define NMV 20000
#define NEV 1000000
#define ETV 500000

#define CHK 8192                  // edges per histogram chunk (2^13)
#define NCH 123                   // ceil(NEV/CHK)
#define WNM 5000                  // merchant hist words (20000 dests / 4 per word)
#define WNU 25000                 // user hist words (100000 / 4)
#define NCA 5                     // merchant scan chunks (4096 dests each)
#define NCB 25                    // user scan chunks
#define HGRID 1954                // ceil(2*NEV/4/256)
#define MBLK 5000                 // merchant agg blocks (NMV/4)
#define G1TM 313                  // merchant layer-1 MFMA tiles (ceil(NMV/64))
#define G2MB 313                  // merchant layer-2 tiles (ceil(NMV/64))
#define PWB 386                   // prep: weight-section blocks

typedef unsigned short u16;
typedef unsigned int u32;
typedef __attribute__((ext_vector_type(8))) short s16x8;
typedef __attribute__((ext_vector_type(4))) float f32x4;
typedef __attribute__((ext_vector_type(2))) unsigned int u32x2;
typedef __attribute__((ext_vector_type(4))) unsigned int u32x4;

__device__ inline u16 bf16r(float f) {  // RTNE float->bf16
  u32 b = __builtin_bit_cast(u32, f);
  u32 r = b + 0x7fffu + ((b >> 16) & 1u);
  return (u16)(r >> 16);
}
__device__ inline float bflo(u32 v) { return __builtin_bit_cast(float, v << 16); }
__device__ inline float bfhi(u32 v) { return __builtin_bit_cast(float, v & 0xffff0000u); }

#define GLOAD_LDS16(src, dst) \
  __builtin_amdgcn_global_load_lds((const __attribute__((address_space(1))) void*)(src), \
                                   (__attribute__((address_space(3))) void*)(dst), 16, 0, 0)

// ---------------- CSR: chunk-local LDS histogram + rank (NO global atomics) ------
__global__ __launch_bounds__(512) void k_hist_lds(
    const int* __restrict__ col_um, u32* __restrict__ rankp_um, u32* __restrict__ cnt_um,
    const int* __restrict__ col_mu, u32* __restrict__ rankp_mu, u32* __restrict__ cnt_mu) {
  __shared__ u32 hist[WNU];  // 100KB (merchant blocks use first WNM words)
  int bid = blockIdx.x, tid = threadIdx.x;
  bool um = bid < NCH;
  const int* col = um ? col_um : col_mu;
  u32* rankp = um ? rankp_um : rankp_mu;
  u32* cntp = um ? cnt_um : cnt_mu;
  int Wn = um ? WNM : WNU;
  int blk = um ? bid : bid - NCH;
  int e0 = blk * CHK;
  for (int i = tid; i < Wn; i += 512) hist[i] = 0;
  __syncthreads();
  #pragma unroll
  for (int it = 0; it < CHK / 2048; ++it) {
    int li = e0 + (it * 512 + tid) * 4;
    if (li < NEV) {
      int4 c = *(const int4*)(col + li);
      int cc[4] = {c.x, c.y, c.z, c.w};
      u32 pk = 0;
      #pragma unroll
      for (int q = 0; q < 4; ++q) {
        int d = cc[q];
        int sh = 8 * (d & 3);
        u32 old = atomicAdd(&hist[d >> 2], 1u << sh);
        pk |= ((old >> sh) & 0xFFu) << (8 * q);
      }
      rankp[li >> 2] = pk;
    }
  }
  __syncthreads();
  u32* dst = cntp + (size_t)blk * Wn;
  for (int i = tid; i < Wn; i += 512) dst[i] = hist[i];
}

// ---- S1: per-dest prefix over chunks (bytes) + per-dest totals T + chunk sums ----
__global__ __launch_bounds__(1024) void k_scan_s1(
    const u32* __restrict__ cnt_um, u32* __restrict__ pre_um,
    const u32* __restrict__ cnt_mu, u32* __restrict__ pre_mu,
    int* __restrict__ T, int* __restrict__ bsum) {
  int b = blockIdx.x;
  const u32* cnt; u32* pre; int Wn; int w0; int* Tout;
  if (b < NCA) { cnt = cnt_um; pre = pre_um; Wn = WNM; w0 = b * 1024; Tout = T; }
  else         { cnt = cnt_mu; pre = pre_mu; Wn = WNU; w0 = (b - NCA) * 1024; Tout = T + NMV; }
  __shared__ int wsum[16];
  int tid = threadIdx.x, lane = tid & 63, w = tid >> 6;
  int wd = w0 + tid;
  int r0 = 0, r1 = 0, r2 = 0, r3 = 0;
  if (wd < Wn) {
    #pragma unroll 4
    for (int bb = 0; bb < NCH; ++bb) {
      u32 v = cnt[(size_t)bb * Wn + wd];
      pre[(size_t)bb * Wn + wd] =
          (u32)r0 | ((u32)r1 << 8) | ((u32)r2 << 16) | ((u32)r3 << 24);
      r0 += v & 0xFF; r1 += (v >> 8) & 0xFF; r2 += (v >> 16) & 0xFF; r3 += (v >> 24) & 0xFF;
    }
    *(int4*)(Tout + wd * 4) = make_int4(r0, r1, r2, r3);
  }
  int tot = r0 + r1 + r2 + r3;
  #pragma unroll
  for (int d = 1; d < 64; d <<= 1) tot += __shfl_xor(tot, d);
  if (lane == 0) wsum[w] = tot;
  __syncthreads();
  if (tid == 0) {
    int a = 0;
    #pragma unroll
    for (int j = 0; j < 16; ++j) a += wsum[j];
    bsum[b] = a;
  }
}

// ---- S3 (with inlined chunk-sum scan): off[c] = exclusive scan of T ----
__global__ __launch_bounds__(1024) void k_scan_s3(int* __restrict__ off_um,
                                                  int* __restrict__ off_mu,
                                                  const int* __restrict__ T,
                                                  const int* __restrict__ bsum) {
  int b = blockIdx.x;
  int N; int c0; int* offo; const int* Tin;
  if (b < NCA) { N = NMV; c0 = b * 4096; offo = off_um; Tin = T; }
  else         { N = NUV; c0 = (b - NCA) * 4096; offo = off_mu; Tin = T + NMV; }
  __shared__ int carry_s;
  __shared__ int wsum[16];
  int tid = threadIdx.x, lane = tid & 63, w = tid >> 6;
  if (tid == 0) {
    int lo = (b < NCA) ? 0 : NCA;
    int c = 0;
    for (int j = lo; j < b; ++j) c += bsum[j];
    carry_s = c;
    if (b == 0) { off_um[NMV] = NEV; off_mu[NUV] = NEV; }
  }
  __syncthreads();
  int carry = carry_s;
  int c = c0 + tid * 4;
  int4 tv = make_int4(0, 0, 0, 0);
  if (c < N) tv = *(const int4*)(Tin + c);
  int p1 = tv.x + tv.y, p2 = p1 + tv.z, p3 = p2 + tv.w;
  int sc = p3;
  #pragma unroll
  for (int d = 1; d < 64; d <<= 1) { int t = __shfl_up(sc, d); if (lane >= d) sc += t; }
  if (lane == 63) wsum[w] = sc;
  __syncthreads();
  if (w == 0 && lane < 16) {
    int ws_ = wsum[lane];
    #pragma unroll
    for (int d = 1; d < 16; d <<= 1) { int t = __shfl_up(ws_, d, 16); if (lane >= d) ws_ += t; }
    wsum[lane] = ws_;
  }
  __syncthreads();
  int ex = sc - p3 + (w ? wsum[w - 1] : 0) + carry;
  if (c < N) *(int4*)(offo + c) = make_int4(ex, ex + tv.x, ex + p1, ex + p2);
}

// ---------------- atomic-free scatter: pos = off[c] + pre2d[chunk][c] + rank ------
__global__ __launch_bounds__(256) void k_scatter3(
    const int* __restrict__ col_um, const int* __restrict__ row_um,
    const u32* __restrict__ rankp_um, const u32* __restrict__ pre_um,
    const int* __restrict__ off_um, int* __restrict__ srow_um,
    const int* __restrict__ col_mu, const int* __restrict__ row_mu,
    const u32* __restrict__ rankp_mu, const u32* __restrict__ pre_mu,
    const int* __restrict__ off_mu, int* __restrict__ srow_mu) {
  int i = (blockIdx.x * 256 + threadIdx.x) * 4;
  if (i >= 2 * NEV) return;
  bool um = i < NEV;
  const int* col = um ? col_um : col_mu;
  const int* row = um ? row_um : row_mu;
  const u32* rankp = um ? rankp_um : rankp_mu;
  const u32* pre = um ? pre_um : pre_mu;
  const int* off = um ? off_um : off_mu;
  int Wn = um ? WNM : WNU;
  int* srow = um ? srow_um : srow_mu;
  int lo = um ? i : i - NEV;
  int blk = lo >> 13;  // CHK = 8192
  const u32* prep = pre + (size_t)blk * Wn;
  int4 c = *(const int4*)(col + lo);
  int4 rr = *(const int4*)(row + lo);
  u32 pk = rankp[lo >> 2];
  int cc[4] = {c.x, c.y, c.z, c.w}, rv[4] = {rr.x, rr.y, rr.z, rr.w};
  #pragma unroll
  for (int q = 0; q < 4; ++q) {
    int d = cc[q];
    int prefix = (int)((prep[d >> 2] >> (8 * (d & 3))) & 0xFF);
    int rank = (int)((pk >> (8 * q)) & 0xFF);
    srow[off[d] + prefix + rank] = rv[q];
  }
}

// ---------------- merged prep: weights (folded Wt2, Wt1, biases) + x cat fill ------
__global__ __launch_bounds__(256) void k_prep(
    const float* __restrict__ x_user, const float* __restrict__ x_merch,
    const float* __restrict__ W1l_um, const float* __restrict__ W1r_um,
    const float* __restrict__ W1l_mu, const float* __restrict__ W1r_mu,
    const float* __restrict__ W2l_um, const float* __restrict__ W2r_um,
    const float* __restrict__ W2l_mu, const float* __restrict__ W2r_mu,
    const float* __restrict__ b2_um, const float* __restrict__ b2_mu,
    const float* __restrict__ Wc1, const float* __restrict__ bc1,
    u16* __restrict__ WtA_u, u16* __restrict__ WtB_u,
    u16* __restrict__ WtA_m, u16* __restrict__ WtB_m,
    u16* __restrict__ Wt1_m, u16* __restrict__ Wt1_u,
    float* __restrict__ bias_u, float* __restrict__ bias_m,
    u32* __restrict__ cat_u, u32* __restrict__ cat_m) {
  int bid = blockIdx.x;
  if (bid < PWB) {
    int t = bid * 256 + threadIdx.x;
    if (t < 65536) {
      int mat = t >> 14, rem = t & 16383;
      int o = rem >> 7, k = rem & 127;
      const float* W2 = mat == 0 ? W2l_mu : mat == 1 ? W2r_mu : mat == 2 ? W2l_um : W2r_um;
      const float* wc = Wc1 + (mat >= 2 ? 128 * 128 : 0) + o;
      float s = 0.f;
      #pragma unroll 4
      for (int j = 0; j < 128; ++j) s += W2[k * 128 + j] * wc[j * 128];
      u16* dst = mat == 0 ? WtA_u : mat == 1 ? WtB_u : mat == 2 ? WtA_m : WtB_m;
      dst[o * 128 + k] = bf16r(s);
    } else if (t < 65536 + 256) {
      int r = t - 65536;
      int o = r & 127;
      if (r < 128) {
        float s = 0.f;
        for (int j = 0; j < 128; ++j) s += b2_mu[j] * Wc1[j * 128 + o];
        bias_u[o] = s;
      } else {
        float s = bc1[o];  // fold bc1 into merchant-side bias
        for (int j = 0; j < 128; ++j) s += b2_um[j] * Wc1[(128 + j) * 128 + o];
        bias_m[o] = s;
      }
    } else if (t < 65792 + 32768) {
      int idx = t - 65792;
      int mat = idx >> 14, rem = idx & 16383;
      int o = rem >> 7, k = rem & 127;
      if (mat == 0) {  // merchant: cat_m = [agg64 | x_merch32 | pad32]
        float v = k < 64 ? W1l_um[k * 128 + o] : (k < 96 ? W1r_um[(k - 64) * 128 + o] : 0.f);
        Wt1_m[o * 128 + k] = bf16r(v);
      } else {         // user: cat_u = [agg32 | x_user64 | pad32]
        float v = k < 32 ? W1l_mu[k * 128 + o] : (k < 96 ? W1r_mu[(k - 32) * 128 + o] : 0.f);
        Wt1_u[o * 128 + k] = bf16r(v);
      }
    }
  } else {
    int id = (bid - PWB) * 256 + threadIdx.x;
    if (id < NUV * 12) {
      int row = id / 12, wg = id % 12;
      if (wg < 8) {
        const float* src = x_user + (size_t)row * 64 + wg * 8;
        float4 a = *(const float4*)src, b = *(const float4*)(src + 4);
        u32x4 r;
        r[0] = (u32)bf16r(a.x) | ((u32)bf16r(a.y) << 16);
        r[1] = (u32)bf16r(a.z) | ((u32)bf16r(a.w) << 16);
        r[2] = (u32)bf16r(b.x) | ((u32)bf16r(b.y) << 16);
        r[3] = (u32)bf16r(b.z) | ((u32)bf16r(b.w) << 16);
        *(u32x4*)(cat_u + (size_t)row * 64 + 16 + wg * 4) = r;
      } else {
        *(u32x4*)(cat_u + (size_t)row * 64 + 48 + (wg - 8) * 4) = (u32x4){0, 0, 0, 0};
      }
    } else if (id < NUV * 12 + NMV * 8) {
      int id2 = id - NUV * 12;
      int row = id2 / 8, wg = id2 % 8;
      if (wg < 4) {
        const float* src = x_merch + (size_t)row * 32 + wg * 8;
        float4 a = *(const float4*)src, b = *(const float4*)(src + 4);
        u32x4 r;
        r[0] = (u32)bf16r(a.x) | ((u32)bf16r(a.y) << 16);
        r[1] = (u32)bf16r(a.z) | ((u32)bf16r(a.w) << 16);
        r[2] = (u32)bf16r(b.x) | ((u32)bf16r(b.y) << 16);
        r[3] = (u32)bf16r(b.z) | ((u32)bf16r(b.w) << 16);
        *(u32x4*)(cat_m + (size_t)row * 64 + 32 + wg * 4) = r;
      } else {
        *(u32x4*)(cat_m + (size_t)row * 64 + 48 + (wg - 4) * 4) = (u32x4){0, 0, 0, 0};
      }
    }
  }
}

// ---------------- merged layer-1 segment-mean (4-deep wide-lane gathers, bf16 out) ----
__global__ __launch_bounds__(256) void k_agg_l1(
    const int* __restrict__ off_um, const int* __restrict__ srow_um,
    const int* __restrict__ off_mu, const int* __restrict__ srow_mu,
    u32* __restrict__ cat_u, u32* __restrict__ cat_m) {
  int bid = blockIdx.x, tid = threadIdx.x;
  int l = tid & 63, g = l >> 3, lr = l & 7;
  if (bid < MBLK) {
    int wid = (bid * 256 + tid) >> 6;
    int s = off_um[wid], t = off_um[wid + 1];
    const u32* gx = cat_u;  // x region at +16
    float a[8] = {};
    int j = s;
    for (; j + 32 <= t; j += 32) {
      int r0 = srow_um[j + g], r1 = srow_um[j + 8 + g];
      int r2 = srow_um[j + 16 + g], r3 = srow_um[j + 24 + g];
      u32x4 v0 = *(const u32x4*)(gx + (size_t)r0 * 64 + 16 + lr * 4);
      u32x4 v1 = *(const u32x4*)(gx + (size_t)r1 * 64 + 16 + lr * 4);
      u32x4 v2 = *(const u32x4*)(gx + (size_t)r2 * 64 + 16 + lr * 4);
      u32x4 v3 = *(const u32x4*)(gx + (size_t)r3 * 64 + 16 + lr * 4);
      #pragma unroll
      for (int k = 0; k < 4; ++k) {
        a[2 * k] += (bflo(v0[k]) + bflo(v1[k])) + (bflo(v2[k]) + bflo(v3[k]));
        a[2 * k + 1] += (bfhi(v0[k]) + bfhi(v1[k])) + (bfhi(v2[k]) + bfhi(v3[k]));
      }
    }
    for (; j + 8 <= t; j += 8) {
      int r0 = srow_um[j + g];
      u32x4 v0 = *(const u32x4*)(gx + (size_t)r0 * 64 + 16 + lr * 4);
      #pragma unroll
      for (int k = 0; k < 4; ++k) { a[2 * k] += bflo(v0[k]); a[2 * k + 1] += bfhi(v0[k]); }
    }
    if (g < t - j) {
      int r0 = srow_um[j + g];
      u32x4 v0 = *(const u32x4*)(gx + (size_t)r0 * 64 + 16 + lr * 4);
      #pragma unroll
      for (int k = 0; k < 4; ++k) { a[2 * k] += bflo(v0[k]); a[2 * k + 1] += bfhi(v0[k]); }
    }
    #pragma unroll
    for (int k = 0; k < 8; ++k) {
      a[k] += __shfl_xor(a[k], 8);
      a[k] += __shfl_xor(a[k], 16);
      a[k] += __shfl_xor(a[k], 32);
    }
    if (g == 0) {
      float inv = 1.f / (float)max(t - s, 1);
      u32x4 o;
      #pragma unroll
      for (int k = 0; k < 4; ++k)
        o[k] = (u32)bf16r(a[2 * k] * inv) | ((u32)bf16r(a[2 * k + 1] * inv) << 16);
      *(u32x4*)(cat_m + (size_t)wid * 64 + lr * 4) = o;
    }
  } else {
    int wid = ((bid - MBLK) * 256 + tid) >> 6;
    int s = off_mu[wid], t = off_mu[wid + 1];
    const u32* gx = cat_m;  // x region at +32
    float a[4] = {};
    int j = s;
    for (; j + 32 <= t; j += 32) {
      int r0 = srow_mu[j + g], r1 = srow_mu[j + 8 + g];
      int r2 = srow_mu[j + 16 + g], r3 = srow_mu[j + 24 + g];
      u32x2 v0 = *(const u32x2*)(gx + (size_t)r0 * 64 + 32 + lr * 2);
      u32x2 v1 = *(const u32x2*)(gx + (size_t)r1 * 64 + 32 + lr * 2);
      u32x2 v2 = *(const u32x2*)(gx + (size_t)r2 * 64 + 32 + lr * 2);
      u32x2 v3 = *(const u32x2*)(gx + (size_t)r3 * 64 + 32 + lr * 2);
      #pragma unroll
      for (int k = 0; k < 2; ++k) {
        a[2 * k] += (bflo(v0[k]) + bflo(v1[k])) + (bflo(v2[k]) + bflo(v3[k]));
        a[2 * k + 1] += (bfhi(v0[k]) + bfhi(v1[k])) + (bfhi(v2[k]) + bfhi(v3[k]));
      }
    }
    for (; j + 8 <= t; j += 8) {
      int r0 = srow_mu[j + g];
      u32x2 v0 = *(const u32x2*)(gx + (size_t)r0 * 64 + 32 + lr * 2);
      #pragma unroll
      for (int k = 0; k < 2; ++k) { a[2 * k] += bflo(v0[k]); a[2 * k + 1] += bfhi(v0[k]); }
    }
    if (g < t - j) {
      int r0 = srow_mu[j + g];
      u32x2 v0 = *(const u32x2*)(gx + (size_t)r0 * 64 + 32 + lr * 2);
      #pragma unroll
      for (int k = 0; k < 2; ++k) { a[2 * k] += bflo(v0[k]); a[2 * k + 1] += bfhi(v0[k]); }
    }
    #pragma unroll
    for (int k = 0; k < 4; ++k) {
      a[k] += __shfl_xor(a[k], 8);
      a[k] += __shfl_xor(a[k], 16);
      a[k] += __shfl_xor(a[k], 32);
    }
    if (g == 0) {
      float inv = 1.f / (float)max(t - s, 1);
      u32x2 o;
      #pragma unroll
      for (int k = 0; k < 2; ++k)
        o[k] = (u32)bf16r(a[2 * k] * inv) | ((u32)bf16r(a[2 * k + 1] * inv) << 16);
      *(u32x2*)(cat_u + (size_t)wid * 64 + lr * 2) = o;
    }
  }
}

// ---------------- layer-1 MFMA GEMM: h = relu(cat @ Wt1^T + b1), bf16 out ----------
__global__ __launch_bounds__(256) void k_gemm1_mfma(
    const u16* __restrict__ cat_m, const u16* __restrict__ Wt1_m,
    const float* __restrict__ b1_um, u16* __restrict__ h_m,
    const u16* __restrict__ cat_u, const u16* __restrict__ Wt1_u,
    const float* __restrict__ b1_mu, u16* __restrict__ h_u) {
  __shared__ u16 Zs[64 * 128];  // 16KB
  int tid = threadIdx.x, bid = blockIdx.x;
  const u16 *cat, *Wt; const float* bias; u16* ho; int nd, r0;
  if (bid < G1TM) { cat = cat_m; Wt = Wt1_m; bias = b1_um; ho = h_m; nd = NMV; r0 = bid * 64; }
  else { cat = cat_u; Wt = Wt1_u; bias = b1_mu; ho = h_u; nd = NUV; r0 = (bid - G1TM) * 64; }
  #pragma unroll
  for (int it = 0; it < 4; ++it) {
    int q = tid + it * 256;
    int rl = q >> 4;
    int cc = (q & 15) ^ (rl & 7);
    int r = r0 + rl; r = r < nd ? r : nd - 1;
    const u16* src = cat + (size_t)r * 128 + cc * 8;
    u16* dst = Zs + (tid >> 6) * 512 + it * 2048;
    GLOAD_LDS16(src, dst);
  }
  __syncthreads();
  int l = tid & 63, wv = tid >> 6;
  int lg = l >> 4, lr = l & 15;
  f32x4 acc[4][2];
  #pragma unroll
  for (int mt = 0; mt < 4; ++mt)
    #pragma unroll
    for (int c = 0; c < 2; ++c) acc[mt][c] = (f32x4){0.f, 0.f, 0.f, 0.f};
  #pragma unroll
  for (int cti = 0; cti < 2; ++cti) {
    int o = (wv * 2 + cti) * 16 + lr;
    const u16* wp = Wt + (size_t)o * 128 + lg * 8;
    s16x8 b[4];
    #pragma unroll
    for (int ks = 0; ks < 4; ++ks) b[ks] = *(const s16x8*)(wp + ks * 32);
    #pragma unroll
    for (int mt = 0; mt < 4; ++mt) {
      int rl = mt * 16 + lr;
      int rb = rl * 256, sw = (rl & 7) << 4;
      #pragma unroll
      for (int ks = 0; ks < 4; ++ks) {
        s16x8 a = *(const s16x8*)((const char*)Zs + ((rb + ks * 64 + lg * 16) ^ sw));
        acc[mt][cti] = __builtin_amdgcn_mfma_f32_16x16x32_bf16(a, b[ks], acc[mt][cti], 0, 0, 0);
      }
    }
  }
  float bv[2];
  #pragma unroll
  for (int cti = 0; cti < 2; ++cti) bv[cti] = bias[(wv * 2 + cti) * 16 + lr];
  #pragma unroll
  for (int mt = 0; mt < 4; ++mt)
    #pragma unroll
    for (int cti = 0; cti < 2; ++cti) {
      int o = (wv * 2 + cti) * 16 + lr;
      #pragma unroll
      for (int rg = 0; rg < 4; ++rg) {
        int r = r0 + mt * 16 + lg * 4 + rg;
        if (r < nd) {
          float v = acc[mt][cti][rg] + bv[cti];
          v = v > 0.f ? v : 0.f;  // layer-1 relu
          ho[(size_t)r * 128 + o] = bf16r(v);
        }
      }
    }
}

// ---------------- FUSED layer-2: gather-mean into LDS + MFMA (no aggb round-trip) ----
// Zh = staged dest h rows (16KB, k 128..255 via Wtr); Za = aggregated means (16KB,
// k 0..127 via Wtl). Each wave aggregates 16 dests; means ds_written with the same
// XOR swizzle the MFMA reads use.
__global__ __launch_bounds__(256) void k_gemm2f(
    const int* __restrict__ off_um, const int* __restrict__ srow_um,
    const int* __restrict__ off_mu, const int* __restrict__ srow_mu,
    const u16* __restrict__ h_m, const u16* __restrict__ h_u,
    const u16* __restrict__ WtA_m, const u16* __restrict__ WtB_m,
    const float* __restrict__ bias_m, u16* __restrict__ pm_b,
    const u16* __restrict__ WtA_u, const u16* __restrict__ WtB_u,
    const float* __restrict__ bias_u, u16* __restrict__ pu_b) {
  __shared__ u16 Zh[64 * 128];  // dest h rows (16KB)
  __shared__ u16 Za[64 * 128];  // gathered means (16KB)
  int tid = threadIdx.x, bid = blockIdx.x;
  const int *off, *srow; const u32* gtab; const u16 *hb, *Wtl, *Wtr;
  const float* bias; u16* zb; int nd, r0;
  if (bid < G2MB) {
    off = off_um; srow = srow_um; gtab = (const u32*)h_u; hb = h_m;
    Wtl = WtA_m; Wtr = WtB_m; bias = bias_m; zb = pm_b; nd = NMV; r0 = bid * 64;
  } else {
    off = off_mu; srow = srow_mu; gtab = (const u32*)h_m; hb = h_u;
    Wtl = WtA_u; Wtr = WtB_u; bias = bias_u; zb = pu_b; nd = NUV; r0 = (bid - G2MB) * 64;
  }
  // stage dest h rows (async; drains at the barrier, hidden under the gather)
  #pragma unroll
  for (int it = 0; it < 4; ++it) {
    int q = tid + it * 256;
    int rl = q >> 4;
    int cc = (q & 15) ^ (rl & 7);
    int r = r0 + rl; r = r < nd ? r : nd - 1;
    GLOAD_LDS16(hb + (size_t)r * 128 + cc * 8, Zh + (tid >> 6) * 512 + it * 2048);
  }
  // gather-aggregate: wave wv handles dests wv*16 .. wv*16+15
  int l = tid & 63, wv = tid >> 6;
  int g = l >> 4, lr = l & 15;
  for (int i = 0; i < 16; ++i) {
    int rl = wv * 16 + i;
    int r = r0 + rl;
    bool ok = r < nd;
    int s = ok ? off[r] : 0, t = ok ? off[r + 1] : 0;
    float a[8] = {};
    int j = s;
    for (; j + 16 <= t; j += 16) {
      int r0e = srow[j + g], r1e = srow[j + 4 + g];
      int r2e = srow[j + 8 + g], r3e = srow[j + 12 + g];
      u32x4 v0 = *(const u32x4*)(gtab + (size_t)r0e * 64 + lr * 4);
      u32x4 v1 = *(const u32x4*)(gtab + (size_t)r1e * 64 + lr * 4);
      u32x4 v2 = *(const u32x4*)(gtab + (size_t)r2e * 64 + lr * 4);
      u32x4 v3 = *(const u32x4*)(gtab + (size_t)r3e * 64 + lr * 4);
      #pragma unroll
      for (int k = 0; k < 4; ++k) {
        a[2 * k] += (bflo(v0[k]) + bflo(v1[k])) + (bflo(v2[k]) + bflo(v3[k]));
        a[2 * k + 1] += (bfhi(v0[k]) + bfhi(v1[k])) + (bfhi(v2[k]) + bfhi(v3[k]));
      }
    }
    for (; j + 4 <= t; j += 4) {
      int r0e = srow[j + g];
      u32x4 v0 = *(const u32x4*)(gtab + (size_t)r0e * 64 + lr * 4);
      #pragma unroll
      for (int k = 0; k < 4; ++k) { a[2 * k] += bflo(v0[k]); a[2 * k + 1] += bfhi(v0[k]); }
    }
    if (g < t - j) {
      int r0e = srow[j + g];
      u32x4 v0 = *(const u32x4*)(gtab + (size_t)r0e * 64 + lr * 4);
      #pragma unroll
      for (int k = 0; k < 4; ++k) { a[2 * k] += bflo(v0[k]); a[2 * k + 1] += bfhi(v0[k]); }
    }
    #pragma unroll
    for (int k = 0; k < 8; ++k) {
      a[k] += __shfl_xor(a[k], 16);
      a[k] += __shfl_xor(a[k], 32);
    }
    if (g == 0) {
      float inv = 1.f / (float)max(t - s, 1);
      u32x4 o;
      #pragma unroll
      for (int k = 0; k < 4; ++k)
        o[k] = ok ? ((u32)bf16r(a[2 * k] * inv) | ((u32)bf16r(a[2 * k + 1] * inv) << 16)) : 0u;
      int byt = (rl * 256 + lr * 16) ^ ((rl & 7) << 4);
      *(u32x4*)((char*)Za + byt) = o;
    }
  }
  __syncthreads();
  int lg = g;  // l >> 4
  f32x4 acc[4][2];
  #pragma unroll
  for (int mt = 0; mt < 4; ++mt)
    #pragma unroll
    for (int c = 0; c < 2; ++c) acc[mt][c] = (f32x4){0.f, 0.f, 0.f, 0.f};
  #pragma unroll
  for (int cti = 0; cti < 2; ++cti) {
    int o = (wv * 2 + cti) * 16 + lr;
    const u16* wpl = Wtl + (size_t)o * 128 + lg * 8;
    const u16* wpr = Wtr + (size_t)o * 128 + lg * 8;
    s16x8 b[8];
    #pragma unroll
    for (int ks = 0; ks < 4; ++ks) b[ks] = *(const s16x8*)(wpl + ks * 32);
    #pragma unroll
    for (int ks = 0; ks < 4; ++ks) b[ks + 4] = *(const s16x8*)(wpr + ks * 32);
    #pragma unroll
    for (int mt = 0; mt < 4; ++mt) {
      int rl = mt * 16 + lr;
      int rb = rl * 256, sw = (rl & 7) << 4;
      #pragma unroll
      for (int ks = 0; ks < 4; ++ks) {
        s16x8 a = *(const s16x8*)((const char*)Za + ((rb + ks * 64 + lg * 16) ^ sw));
        acc[mt][cti] = __builtin_amdgcn_mfma_f32_16x16x32_bf16(a, b[ks], acc[mt][cti], 0, 0, 0);
      }
      #pragma unroll
      for (int ks = 0; ks < 4; ++ks) {
        s16x8 a = *(const s16x8*)((const char*)Zh + ((rb + ks * 64 + lg * 16) ^ sw));
        acc[mt][cti] = __builtin_amdgcn_mfma_f32_16x16x32_bf16(a, b[ks + 4], acc[mt][cti], 0, 0, 0);
      }
    }
  }
  float bv[2];
  #pragma unroll
  for (int cti = 0; cti < 2; ++cti) bv[cti] = bias[(wv * 2 + cti) * 16 + lr];
  #pragma unroll
  for (int mt = 0; mt < 4; ++mt)
    #pragma unroll
    for (int cti = 0; cti < 2; ++cti) {
      int o = (wv * 2 + cti) * 16 + lr;
      #pragma unroll
      for (int rg = 0; rg < 4; ++rg) {
        int r = r0 + mt * 16 + lg * 4 + rg;
        if (r < nd) zb[(size_t)r * 128 + o] = bf16r(acc[mt][cti][rg] + bv[cti]);
      }
    }
}

// ---------------- edge op: out[e] = Wc2 . relu(pu[row_t[e]] + pm[col_t[e]]) + bc2 ----------------
__global__ __launch_bounds__(256) void k_edge(
    const u32* __restrict__ pu, const u32* __restrict__ pm,
    const int* __restrict__ row_t, const int* __restrict__ col_t,
    const float* __restrict__ Wc2, const float* __restrict__ bc2,
    float* __restrict__ out) {
  __shared__ float res[256];
  int tid = threadIdx.x, l = tid & 63, wv = tid >> 6;
  int lr = l & 15, g = l >> 4;
  float w2v[8];
  #pragma unroll
  for (int q = 0; q < 8; ++q) w2v[q] = Wc2[lr * 8 + q];
  int base = blockIdx.x * 256 + wv * 64;
  #pragma unroll 2
  for (int it = 0; it < 16; ++it) {
    int e = base + it * 4 + g;
    int ec = e < ETV ? e : ETV - 1;
    int r = row_t[ec], c = col_t[ec];
    u32x4 a = *(const u32x4*)(pu + (size_t)r * 64 + lr * 4);
    u32x4 b = *(const u32x4*)(pm + (size_t)c * 64 + lr * 4);
    float p = 0.f;
    #pragma unroll
    for (int q = 0; q < 4; ++q) {
      float h0 = bflo(a[q]) + bflo(b[q]);
      float h1 = bfhi(a[q]) + bfhi(b[q]);
      h0 = h0 > 0.f ? h0 : 0.f;
      h1 = h1 > 0.f ? h1 : 0.f;
      p += h0 * w2v[2 * q] + h1 * w2v[2 * q + 1];
    }
    p += __shfl_xor(p, 1); p += __shfl_xor(p, 2);
    p += __shfl_xor(p, 4); p += __shfl_xor(p, 8);
    if (lr == 0) res[wv * 64 + it * 4 + g] = p;
  }
  __syncthreads();
  int eo = blockIdx.x * 256 + tid;
  if (eo < ETV) out[eo] = res[tid] + bc2[0];
}

extern "C" void kernel_launch(void* const* d_in, const int* in_sizes, int n_in,
                              void* d_out, int out_size, void* d_ws, size_t ws_size,
                              hipStream_t stream) {
  const float* x_user  = (const float*)d_in[0];
  const float* x_merch = (const float*)d_in[1];
  const int* row_um = (const int*)d_in[2]; const int* col_um = (const int*)d_in[3];
  const int* row_mu = (const int*)d_in[4]; const int* col_mu = (const int*)d_in[5];
  const int* row_t  = (const int*)d_in[6]; const int* col_t  = (const int*)d_in[7];
  const float* W1l_um = (const float*)d_in[8];  const float* W1r_um = (const float*)d_in[9];  const float* b1_um = (const float*)d_in[10];
  const float* W1l_mu = (const float*)d_in[11]; const float* W1r_mu = (const float*)d_in[12]; const float* b1_mu = (const float*)d_in[13];
  const float* W2l_um = (const float*)d_in[14]; const float* W2r_um = (const float*)d_in[15]; const float* b2_um = (const float*)d_in[16];
  const float* W2l_mu = (const float*)d_in[17]; const float* W2r_mu = (const float*)d_in[18]; const float* b2_mu = (const float*)d_in[19];
  const float* Wc1 = (const float*)d_in[20]; const float* bc1 = (const float*)d_in[21];
  const float* Wc2 = (const float*)d_in[22]; const float* bc2 = (const float*)d_in[23];
  float* out = (float*)d_out;

  char* ws = (char*)d_ws;
  size_t p = 0;
  auto alloc = [&](size_t bytes) -> char* {
    char* r = ws + p;
    p = (p + bytes + 255) & ~(size_t)255;
    return r;
  };
  u32* cnt_um = (u32*)alloc((size_t)NCH * WNM * 4);     // per-chunk byte counters
  u32* cnt_mu = (u32*)alloc((size_t)NCH * WNU * 4);
  u32* pre_um = (u32*)alloc((size_t)NCH * WNM * 4);     // per-chunk byte prefixes
  u32* pre_mu = (u32*)alloc((size_t)NCH * WNU * 4);
  u32* rankp_um = (u32*)alloc((size_t)(NEV / 4) * 4);   // packed chunk-local ranks
  u32* rankp_mu = (u32*)alloc((size_t)(NEV / 4) * 4);
  int* off_um = (int*)alloc((size_t)(NMV + 4) * 4);
  int* off_mu = (int*)alloc((size_t)(NUV + 4) * 4);
  int* T    = (int*)alloc((size_t)(NMV + NUV) * 4);
  int* bsum = (int*)alloc((size_t)(NCA + NCB) * 4);
  int* srow_um = (int*)alloc((size_t)NEV * 4);
  int* srow_mu = (int*)alloc((size_t)NEV * 4);
  u16* cat_m = (u16*)alloc((size_t)NMV * 128 * 2);       // [agg64|xm32|pad32] bf16
  u16* cat_u = (u16*)alloc((size_t)NUV * 128 * 2);       // [agg32|xu64|pad32] bf16
  u16* h_m   = (u16*)alloc((size_t)NMV * 128 * 2);       // bf16 hidden
  u16* h_u   = (u16*)alloc((size_t)NUV * 128 * 2);
  u16* pm_b  = (u16*)alloc((size_t)NMV * 128 * 2);       // folded classifier projections (bf16)
  u16* pu_b  = (u16*)alloc((size_t)NUV * 128 * 2);
  u16* WtA_u = (u16*)alloc((size_t)128 * 128 * 2);
  u16* WtB_u = (u16*)alloc((size_t)128 * 128 * 2);
  u16* WtA_m = (u16*)alloc((size_t)128 * 128 * 2);
  u16* WtB_m = (u16*)alloc((size_t)128 * 128 * 2);
  u16* Wt1_m = (u16*)alloc((size_t)128 * 128 * 2);
  u16* Wt1_u = (u16*)alloc((size_t)128 * 128 * 2);
  float* bias_u = (float*)alloc(128 * 4);
  float* bias_m = (float*)alloc(128 * 4);
  if (p > ws_size) return;  // workspace too small: fail loudly via absmax

  // merged prep (weights + cat x-region fill)
  k_prep<<<PWB + (NUV * 12 + NMV * 8 + 255) / 256, 256, 0, stream>>>(
      x_user, x_merch, W1l_um, W1r_um, W1l_mu, W1r_mu,
      W2l_um, W2r_um, W2l_mu, W2r_mu, b2_um, b2_mu, Wc1, bc1,
      WtA_u, WtB_u, WtA_m, WtB_m, Wt1_m, Wt1_u, bias_u, bias_m,
      (u32*)cat_u, (u32*)cat_m);
  // CSR build: LDS histogram (0 global atomics), byte prefix planes, off scan, scatter
  k_hist_lds<<<2 * NCH, 512, 0, stream>>>(col_um, rankp_um, cnt_um,
                                          col_mu, rankp_mu, cnt_mu);
  k_scan_s1<<<NCA + NCB, 1024, 0, stream>>>(cnt_um, pre_um, cnt_mu, pre_mu, T, bsum);
  k_scan_s3<<<NCA + NCB, 1024, 0, stream>>>(off_um, off_mu, T, bsum);
  k_scatter3<<<HGRID, 256, 0, stream>>>(col_um, row_um, rankp_um, pre_um, off_um, srow_um,
                                        col_mu, row_mu, rankp_mu, pre_mu, off_mu, srow_mu);
  // layer 1: deep-ILP bf16 gathers into cat agg-columns, then MFMA GEMM -> h
  k_agg_l1<<<MBLK + NUV / 4, 256, 0, stream>>>(off_um, srow_um, off_mu, srow_mu,
                                               (u32*)cat_u, (u32*)cat_m);
  k_gemm1_mfma<<<G1TM + (NUV + 63) / 64, 256, 0, stream>>>(cat_m, Wt1_m, b1_um, h_m,
                                                           cat_u, Wt1_u, b1_mu, h_u);
  // layer 2 FUSED: gather-mean directly into LDS + MFMA with folded classifier weights
  k_gemm2f<<<G2MB + (NUV + 63) / 64, 256, 0, stream>>>(
      off_um, srow_um, off_mu, srow_mu, h_m, h_u,
      WtA_m, WtB_m, bias_m, pm_b, WtA_u, WtB_u, bias_u, pu_b);
  // edge classifier: gather + relu + dot
  k_edge<<<(ETV + 255) / 256, 256, 0, stream>>>((const u32*)pu_b, (const u32*)pm_b,
                                                row_t, col_t, Wc2, bc2, out);
}

// Round 16
// 326.238 us; speedup vs baseline: 1.2592x; 1.2592x over previous
//
#include <hip/hip_runtime.h>
#include <hip/hip_bf16.h>

// Hetero-SAGE: LDS-histogram CSR build (zero global atomics) + deep-ILP wide-lane
// gathers + all-bf16-MFMA GEMMs with folded classifier (z@Wc1 folded into layer 2).
// (R15 fusion reverted: separate agg_l2 + gemm2 keeps gather MLP high.)
#define NUV 100000
#define NMV 20000
#define NEV 1000000
#define ETV 500000

#define CHK 8192                  // edges per histogram chunk (2^13)
#define NCH 123                   // ceil(NEV/CHK)
#define WNM 5000                  // merchant hist words (20000 dests / 4 per word)
#define WNU 25000                 // user hist words (100000 / 4)
#define NCA 5                     // merchant scan chunks (4096 dests each)
#define NCB 25                    // user scan chunks
#define HGRID 1954                // ceil(2*NEV/4/256)
#define MBLK 5000                 // merchant agg blocks (NMV/4)
#define G1TM 313                  // merchant layer-1 MFMA tiles (ceil(NMV/64))
#define G2MB 313                  // merchant layer-2 tiles (ceil(NMV/64))
#define PWB 386                   // prep: weight-section blocks

typedef unsigned short u16;
typedef unsigned int u32;
typedef __attribute__((ext_vector_type(8))) short s16x8;
typedef __attribute__((ext_vector_type(4))) float f32x4;
typedef __attribute__((ext_vector_type(2))) unsigned int u32x2;
typedef __attribute__((ext_vector_type(4))) unsigned int u32x4;

__device__ inline u16 bf16r(float f) {  // RTNE float->bf16
  u32 b = __builtin_bit_cast(u32, f);
  u32 r = b + 0x7fffu + ((b >> 16) & 1u);
  return (u16)(r >> 16);
}
__device__ inline float bflo(u32 v) { return __builtin_bit_cast(float, v << 16); }
__device__ inline float bfhi(u32 v) { return __builtin_bit_cast(float, v & 0xffff0000u); }

#define GLOAD_LDS16(src, dst) \
  __builtin_amdgcn_global_load_lds((const __attribute__((address_space(1))) void*)(src), \
                                   (__attribute__((address_space(3))) void*)(dst), 16, 0, 0)

// ---------------- CSR: chunk-local LDS histogram + rank (NO global atomics) ------
__global__ __launch_bounds__(512) void k_hist_lds(
    const int* __restrict__ col_um, u32* __restrict__ rankp_um, u32* __restrict__ cnt_um,
    const int* __restrict__ col_mu, u32* __restrict__ rankp_mu, u32* __restrict__ cnt_mu) {
  __shared__ u32 hist[WNU];  // 100KB (merchant blocks use first WNM words)
  int bid = blockIdx.x, tid = threadIdx.x;
  bool um = bid < NCH;
  const int* col = um ? col_um : col_mu;
  u32* rankp = um ? rankp_um : rankp_mu;
  u32* cntp = um ? cnt_um : cnt_mu;
  int Wn = um ? WNM : WNU;
  int blk = um ? bid : bid - NCH;
  int e0 = blk * CHK;
  for (int i = tid; i < Wn; i += 512) hist[i] = 0;
  __syncthreads();
  #pragma unroll
  for (int it = 0; it < CHK / 2048; ++it) {
    int li = e0 + (it * 512 + tid) * 4;
    if (li < NEV) {
      int4 c = *(const int4*)(col + li);
      int cc[4] = {c.x, c.y, c.z, c.w};
      u32 pk = 0;
      #pragma unroll
      for (int q = 0; q < 4; ++q) {
        int d = cc[q];
        int sh = 8 * (d & 3);
        u32 old = atomicAdd(&hist[d >> 2], 1u << sh);
        pk |= ((old >> sh) & 0xFFu) << (8 * q);
      }
      rankp[li >> 2] = pk;
    }
  }
  __syncthreads();
  u32* dst = cntp + (size_t)blk * Wn;
  for (int i = tid; i < Wn; i += 512) dst[i] = hist[i];
}

// ---- S1: per-dest prefix over chunks (bytes) + per-dest totals T + chunk sums ----
__global__ __launch_bounds__(1024) void k_scan_s1(
    const u32* __restrict__ cnt_um, u32* __restrict__ pre_um,
    const u32* __restrict__ cnt_mu, u32* __restrict__ pre_mu,
    int* __restrict__ T, int* __restrict__ bsum) {
  int b = blockIdx.x;
  const u32* cnt; u32* pre; int Wn; int w0; int* Tout;
  if (b < NCA) { cnt = cnt_um; pre = pre_um; Wn = WNM; w0 = b * 1024; Tout = T; }
  else         { cnt = cnt_mu; pre = pre_mu; Wn = WNU; w0 = (b - NCA) * 1024; Tout = T + NMV; }
  __shared__ int wsum[16];
  int tid = threadIdx.x, lane = tid & 63, w = tid >> 6;
  int wd = w0 + tid;
  int r0 = 0, r1 = 0, r2 = 0, r3 = 0;
  if (wd < Wn) {
    #pragma unroll 4
    for (int bb = 0; bb < NCH; ++bb) {
      u32 v = cnt[(size_t)bb * Wn + wd];
      pre[(size_t)bb * Wn + wd] =
          (u32)r0 | ((u32)r1 << 8) | ((u32)r2 << 16) | ((u32)r3 << 24);
      r0 += v & 0xFF; r1 += (v >> 8) & 0xFF; r2 += (v >> 16) & 0xFF; r3 += (v >> 24) & 0xFF;
    }
    *(int4*)(Tout + wd * 4) = make_int4(r0, r1, r2, r3);
  }
  int tot = r0 + r1 + r2 + r3;
  #pragma unroll
  for (int d = 1; d < 64; d <<= 1) tot += __shfl_xor(tot, d);
  if (lane == 0) wsum[w] = tot;
  __syncthreads();
  if (tid == 0) {
    int a = 0;
    #pragma unroll
    for (int j = 0; j < 16; ++j) a += wsum[j];
    bsum[b] = a;
  }
}

// ---- S3 (with inlined chunk-sum scan): off[c] = exclusive scan of T ----
__global__ __launch_bounds__(1024) void k_scan_s3(int* __restrict__ off_um,
                                                  int* __restrict__ off_mu,
                                                  const int* __restrict__ T,
                                                  const int* __restrict__ bsum) {
  int b = blockIdx.x;
  int N; int c0; int* offo; const int* Tin;
  if (b < NCA) { N = NMV; c0 = b * 4096; offo = off_um; Tin = T; }
  else         { N = NUV; c0 = (b - NCA) * 4096; offo = off_mu; Tin = T + NMV; }
  __shared__ int carry_s;
  __shared__ int wsum[16];
  int tid = threadIdx.x, lane = tid & 63, w = tid >> 6;
  if (tid == 0) {
    int lo = (b < NCA) ? 0 : NCA;
    int c = 0;
    for (int j = lo; j < b; ++j) c += bsum[j];
    carry_s = c;
    if (b == 0) { off_um[NMV] = NEV; off_mu[NUV] = NEV; }
  }
  __syncthreads();
  int carry = carry_s;
  int c = c0 + tid * 4;
  int4 tv = make_int4(0, 0, 0, 0);
  if (c < N) tv = *(const int4*)(Tin + c);
  int p1 = tv.x + tv.y, p2 = p1 + tv.z, p3 = p2 + tv.w;
  int sc = p3;
  #pragma unroll
  for (int d = 1; d < 64; d <<= 1) { int t = __shfl_up(sc, d); if (lane >= d) sc += t; }
  if (lane == 63) wsum[w] = sc;
  __syncthreads();
  if (w == 0 && lane < 16) {
    int ws_ = wsum[lane];
    #pragma unroll
    for (int d = 1; d < 16; d <<= 1) { int t = __shfl_up(ws_, d, 16); if (lane >= d) ws_ += t; }
    wsum[lane] = ws_;
  }
  __syncthreads();
  int ex = sc - p3 + (w ? wsum[w - 1] : 0) + carry;
  if (c < N) *(int4*)(offo + c) = make_int4(ex, ex + tv.x, ex + p1, ex + p2);
}

// ---------------- atomic-free scatter: pos = off[c] + pre2d[chunk][c] + rank ------
__global__ __launch_bounds__(256) void k_scatter3(
    const int* __restrict__ col_um, const int* __restrict__ row_um,
    const u32* __restrict__ rankp_um, const u32* __restrict__ pre_um,
    const int* __restrict__ off_um, int* __restrict__ srow_um,
    const int* __restrict__ col_mu, const int* __restrict__ row_mu,
    const u32* __restrict__ rankp_mu, const u32* __restrict__ pre_mu,
    const int* __restrict__ off_mu, int* __restrict__ srow_mu) {
  int i = (blockIdx.x * 256 + threadIdx.x) * 4;
  if (i >= 2 * NEV) return;
  bool um = i < NEV;
  const int* col = um ? col_um : col_mu;
  const int* row = um ? row_um : row_mu;
  const u32* rankp = um ? rankp_um : rankp_mu;
  const u32* pre = um ? pre_um : pre_mu;
  const int* off = um ? off_um : off_mu;
  int Wn = um ? WNM : WNU;
  int* srow = um ? srow_um : srow_mu;
  int lo = um ? i : i - NEV;
  int blk = lo >> 13;  // CHK = 8192
  const u32* prep = pre + (size_t)blk * Wn;
  int4 c = *(const int4*)(col + lo);
  int4 rr = *(const int4*)(row + lo);
  u32 pk = rankp[lo >> 2];
  int cc[4] = {c.x, c.y, c.z, c.w}, rv[4] = {rr.x, rr.y, rr.z, rr.w};
  #pragma unroll
  for (int q = 0; q < 4; ++q) {
    int d = cc[q];
    int prefix = (int)((prep[d >> 2] >> (8 * (d & 3))) & 0xFF);
    int rank = (int)((pk >> (8 * q)) & 0xFF);
    srow[off[d] + prefix + rank] = rv[q];
  }
}

// ---------------- merged prep: weights (folded Wt2, Wt1, biases) + x cat fill ------
__global__ __launch_bounds__(256) void k_prep(
    const float* __restrict__ x_user, const float* __restrict__ x_merch,
    const float* __restrict__ W1l_um, const float* __restrict__ W1r_um,
    const float* __restrict__ W1l_mu, const float* __restrict__ W1r_mu,
    const float* __restrict__ W2l_um, const float* __restrict__ W2r_um,
    const float* __restrict__ W2l_mu, const float* __restrict__ W2r_mu,
    const float* __restrict__ b2_um, const float* __restrict__ b2_mu,
    const float* __restrict__ Wc1, const float* __restrict__ bc1,
    u16* __restrict__ WtA_u, u16* __restrict__ WtB_u,
    u16* __restrict__ WtA_m, u16* __restrict__ WtB_m,
    u16* __restrict__ Wt1_m, u16* __restrict__ Wt1_u,
    float* __restrict__ bias_u, float* __restrict__ bias_m,
    u32* __restrict__ cat_u, u32* __restrict__ cat_m) {
  int bid = blockIdx.x;
  if (bid < PWB) {
    int t = bid * 256 + threadIdx.x;
    if (t < 65536) {
      int mat = t >> 14, rem = t & 16383;
      int o = rem >> 7, k = rem & 127;
      const float* W2 = mat == 0 ? W2l_mu : mat == 1 ? W2r_mu : mat == 2 ? W2l_um : W2r_um;
      const float* wc = Wc1 + (mat >= 2 ? 128 * 128 : 0) + o;
      float s = 0.f;
      #pragma unroll 4
      for (int j = 0; j < 128; ++j) s += W2[k * 128 + j] * wc[j * 128];
      u16* dst = mat == 0 ? WtA_u : mat == 1 ? WtB_u : mat == 2 ? WtA_m : WtB_m;
      dst[o * 128 + k] = bf16r(s);
    } else if (t < 65536 + 256) {
      int r = t - 65536;
      int o = r & 127;
      if (r < 128) {
        float s = 0.f;
        for (int j = 0; j < 128; ++j) s += b2_mu[j] * Wc1[j * 128 + o];
        bias_u[o] = s;
      } else {
        float s = bc1[o];  // fold bc1 into merchant-side bias
        for (int j = 0; j < 128; ++j) s += b2_um[j] * Wc1[(128 + j) * 128 + o];
        bias_m[o] = s;
      }
    } else if (t < 65792 + 32768) {
      int idx = t - 65792;
      int mat = idx >> 14, rem = idx & 16383;
      int o = rem >> 7, k = rem & 127;
      if (mat == 0) {  // merchant: cat_m = [agg64 | x_merch32 | pad32]
        float v = k < 64 ? W1l_um[k * 128 + o] : (k < 96 ? W1r_um[(k - 64) * 128 + o] : 0.f);
        Wt1_m[o * 128 + k] = bf16r(v);
      } else {         // user: cat_u = [agg32 | x_user64 | pad32]
        float v = k < 32 ? W1l_mu[k * 128 + o] : (k < 96 ? W1r_mu[(k - 32) * 128 + o] : 0.f);
        Wt1_u[o * 128 + k] = bf16r(v);
      }
    }
  } else {
    int id = (bid - PWB) * 256 + threadIdx.x;
    if (id < NUV * 12) {
      int row = id / 12, wg = id % 12;
      if (wg < 8) {
        const float* src = x_user + (size_t)row * 64 + wg * 8;
        float4 a = *(const float4*)src, b = *(const float4*)(src + 4);
        u32x4 r;
        r[0] = (u32)bf16r(a.x) | ((u32)bf16r(a.y) << 16);
        r[1] = (u32)bf16r(a.z) | ((u32)bf16r(a.w) << 16);
        r[2] = (u32)bf16r(b.x) | ((u32)bf16r(b.y) << 16);
        r[3] = (u32)bf16r(b.z) | ((u32)bf16r(b.w) << 16);
        *(u32x4*)(cat_u + (size_t)row * 64 + 16 + wg * 4) = r;
      } else {
        *(u32x4*)(cat_u + (size_t)row * 64 + 48 + (wg - 8) * 4) = (u32x4){0, 0, 0, 0};
      }
    } else if (id < NUV * 12 + NMV * 8) {
      int id2 = id - NUV * 12;
      int row = id2 / 8, wg = id2 % 8;
      if (wg < 4) {
        const float* src = x_merch + (size_t)row * 32 + wg * 8;
        float4 a = *(const float4*)src, b = *(const float4*)(src + 4);
        u32x4 r;
        r[0] = (u32)bf16r(a.x) | ((u32)bf16r(a.y) << 16);
        r[1] = (u32)bf16r(a.z) | ((u32)bf16r(a.w) << 16);
        r[2] = (u32)bf16r(b.x) | ((u32)bf16r(b.y) << 16);
        r[3] = (u32)bf16r(b.z) | ((u32)bf16r(b.w) << 16);
        *(u32x4*)(cat_m + (size_t)row * 64 + 32 + wg * 4) = r;
      } else {
        *(u32x4*)(cat_m + (size_t)row * 64 + 48 + (wg - 4) * 4) = (u32x4){0, 0, 0, 0};
      }
    }
  }
}

// ---------------- merged layer-1 segment-mean (4-deep wide-lane gathers, bf16 out) ----
__global__ __launch_bounds__(256) void k_agg_l1(
    const int* __restrict__ off_um, const int* __restrict__ srow_um,
    const int* __restrict__ off_mu, const int* __restrict__ srow_mu,
    u32* __restrict__ cat_u, u32* __restrict__ cat_m) {
  int bid = blockIdx.x, tid = threadIdx.x;
  int l = tid & 63, g = l >> 3, lr = l & 7;
  if (bid < MBLK) {
    int wid = (bid * 256 + tid) >> 6;
    int s = off_um[wid], t = off_um[wid + 1];
    const u32* gx = cat_u;  // x region at +16
    float a[8] = {};
    int j = s;
    for (; j + 32 <= t; j += 32) {
      int r0 = srow_um[j + g], r1 = srow_um[j + 8 + g];
      int r2 = srow_um[j + 16 + g], r3 = srow_um[j + 24 + g];
      u32x4 v0 = *(const u32x4*)(gx + (size_t)r0 * 64 + 16 + lr * 4);
      u32x4 v1 = *(const u32x4*)(gx + (size_t)r1 * 64 + 16 + lr * 4);
      u32x4 v2 = *(const u32x4*)(gx + (size_t)r2 * 64 + 16 + lr * 4);
      u32x4 v3 = *(const u32x4*)(gx + (size_t)r3 * 64 + 16 + lr * 4);
      #pragma unroll
      for (int k = 0; k < 4; ++k) {
        a[2 * k] += (bflo(v0[k]) + bflo(v1[k])) + (bflo(v2[k]) + bflo(v3[k]));
        a[2 * k + 1] += (bfhi(v0[k]) + bfhi(v1[k])) + (bfhi(v2[k]) + bfhi(v3[k]));
      }
    }
    for (; j + 8 <= t; j += 8) {
      int r0 = srow_um[j + g];
      u32x4 v0 = *(const u32x4*)(gx + (size_t)r0 * 64 + 16 + lr * 4);
      #pragma unroll
      for (int k = 0; k < 4; ++k) { a[2 * k] += bflo(v0[k]); a[2 * k + 1] += bfhi(v0[k]); }
    }
    if (g < t - j) {
      int r0 = srow_um[j + g];
      u32x4 v0 = *(const u32x4*)(gx + (size_t)r0 * 64 + 16 + lr * 4);
      #pragma unroll
      for (int k = 0; k < 4; ++k) { a[2 * k] += bflo(v0[k]); a[2 * k + 1] += bfhi(v0[k]); }
    }
    #pragma unroll
    for (int k = 0; k < 8; ++k) {
      a[k] += __shfl_xor(a[k], 8);
      a[k] += __shfl_xor(a[k], 16);
      a[k] += __shfl_xor(a[k], 32);
    }
    if (g == 0) {
      float inv = 1.f / (float)max(t - s, 1);
      u32x4 o;
      #pragma unroll
      for (int k = 0; k < 4; ++k)
        o[k] = (u32)bf16r(a[2 * k] * inv) | ((u32)bf16r(a[2 * k + 1] * inv) << 16);
      *(u32x4*)(cat_m + (size_t)wid * 64 + lr * 4) = o;
    }
  } else {
    int wid = ((bid - MBLK) * 256 + tid) >> 6;
    int s = off_mu[wid], t = off_mu[wid + 1];
    const u32* gx = cat_m;  // x region at +32
    float a[4] = {};
    int j = s;
    for (; j + 32 <= t; j += 32) {
      int r0 = srow_mu[j + g], r1 = srow_mu[j + 8 + g];
      int r2 = srow_mu[j + 16 + g], r3 = srow_mu[j + 24 + g];
      u32x2 v0 = *(const u32x2*)(gx + (size_t)r0 * 64 + 32 + lr * 2);
      u32x2 v1 = *(const u32x2*)(gx + (size_t)r1 * 64 + 32 + lr * 2);
      u32x2 v2 = *(const u32x2*)(gx + (size_t)r2 * 64 + 32 + lr * 2);
      u32x2 v3 = *(const u32x2*)(gx + (size_t)r3 * 64 + 32 + lr * 2);
      #pragma unroll
      for (int k = 0; k < 2; ++k) {
        a[2 * k] += (bflo(v0[k]) + bflo(v1[k])) + (bflo(v2[k]) + bflo(v3[k]));
        a[2 * k + 1] += (bfhi(v0[k]) + bfhi(v1[k])) + (bfhi(v2[k]) + bfhi(v3[k]));
      }
    }
    for (; j + 8 <= t; j += 8) {
      int r0 = srow_mu[j + g];
      u32x2 v0 = *(const u32x2*)(gx + (size_t)r0 * 64 + 32 + lr * 2);
      #pragma unroll
      for (int k = 0; k < 2; ++k) { a[2 * k] += bflo(v0[k]); a[2 * k + 1] += bfhi(v0[k]); }
    }
    if (g < t - j) {
      int r0 = srow_mu[j + g];
      u32x2 v0 = *(const u32x2*)(gx + (size_t)r0 * 64 + 32 + lr * 2);
      #pragma unroll
      for (int k = 0; k < 2; ++k) { a[2 * k] += bflo(v0[k]); a[2 * k + 1] += bfhi(v0[k]); }
    }
    #pragma unroll
    for (int k = 0; k < 4; ++k) {
      a[k] += __shfl_xor(a[k], 8);
      a[k] += __shfl_xor(a[k], 16);
      a[k] += __shfl_xor(a[k], 32);
    }
    if (g == 0) {
      float inv = 1.f / (float)max(t - s, 1);
      u32x2 o;
      #pragma unroll
      for (int k = 0; k < 2; ++k)
        o[k] = (u32)bf16r(a[2 * k] * inv) | ((u32)bf16r(a[2 * k + 1] * inv) << 16);
      *(u32x2*)(cat_u + (size_t)wid * 64 + lr * 2) = o;
    }
  }
}

// ---------------- layer-1 MFMA GEMM: h = relu(cat @ Wt1^T + b1), bf16 out ----------
__global__ __launch_bounds__(256) void k_gemm1_mfma(
    const u16* __restrict__ cat_m, const u16* __restrict__ Wt1_m,
    const float* __restrict__ b1_um, u16* __restrict__ h_m,
    const u16* __restrict__ cat_u, const u16* __restrict__ Wt1_u,
    const float* __restrict__ b1_mu, u16* __restrict__ h_u) {
  __shared__ u16 Zs[64 * 128];  // 16KB
  int tid = threadIdx.x, bid = blockIdx.x;
  const u16 *cat, *Wt; const float* bias; u16* ho; int nd, r0;
  if (bid < G1TM) { cat = cat_m; Wt = Wt1_m; bias = b1_um; ho = h_m; nd = NMV; r0 = bid * 64; }
  else { cat = cat_u; Wt = Wt1_u; bias = b1_mu; ho = h_u; nd = NUV; r0 = (bid - G1TM) * 64; }
  #pragma unroll
  for (int it = 0; it < 4; ++it) {
    int q = tid + it * 256;
    int rl = q >> 4;
    int cc = (q & 15) ^ (rl & 7);
    int r = r0 + rl; r = r < nd ? r : nd - 1;
    const u16* src = cat + (size_t)r * 128 + cc * 8;
    u16* dst = Zs + (tid >> 6) * 512 + it * 2048;
    GLOAD_LDS16(src, dst);
  }
  __syncthreads();
  int l = tid & 63, wv = tid >> 6;
  int lg = l >> 4, lr = l & 15;
  f32x4 acc[4][2];
  #pragma unroll
  for (int mt = 0; mt < 4; ++mt)
    #pragma unroll
    for (int c = 0; c < 2; ++c) acc[mt][c] = (f32x4){0.f, 0.f, 0.f, 0.f};
  #pragma unroll
  for (int cti = 0; cti < 2; ++cti) {
    int o = (wv * 2 + cti) * 16 + lr;
    const u16* wp = Wt + (size_t)o * 128 + lg * 8;
    s16x8 b[4];
    #pragma unroll
    for (int ks = 0; ks < 4; ++ks) b[ks] = *(const s16x8*)(wp + ks * 32);
    #pragma unroll
    for (int mt = 0; mt < 4; ++mt) {
      int rl = mt * 16 + lr;
      int rb = rl * 256, sw = (rl & 7) << 4;
      #pragma unroll
      for (int ks = 0; ks < 4; ++ks) {
        s16x8 a = *(const s16x8*)((const char*)Zs + ((rb + ks * 64 + lg * 16) ^ sw));
        acc[mt][cti] = __builtin_amdgcn_mfma_f32_16x16x32_bf16(a, b[ks], acc[mt][cti], 0, 0, 0);
      }
    }
  }
  float bv[2];
  #pragma unroll
  for (int cti = 0; cti < 2; ++cti) bv[cti] = bias[(wv * 2 + cti) * 16 + lr];
  #pragma unroll
  for (int mt = 0; mt < 4; ++mt)
    #pragma unroll
    for (int cti = 0; cti < 2; ++cti) {
      int o = (wv * 2 + cti) * 16 + lr;
      #pragma unroll
      for (int rg = 0; rg < 4; ++rg) {
        int r = r0 + mt * 16 + lg * 4 + rg;
        if (r < nd) {
          float v = acc[mt][cti][rg] + bv[cti];
          v = v > 0.f ? v : 0.f;  // layer-1 relu
          ho[(size_t)r * 128 + o] = bf16r(v);
        }
      }
    }
}

// ---------------- merged layer-2 segment-mean (4-deep wide-lane bf16 gather) --------
__global__ __launch_bounds__(256) void k_agg_l2(
    const int* __restrict__ off_um, const int* __restrict__ srow_um,
    const u16* __restrict__ h_u, u16* __restrict__ aggb_m,
    const int* __restrict__ off_mu, const int* __restrict__ srow_mu,
    const u16* __restrict__ h_m, u16* __restrict__ aggb_u) {
  int bid = blockIdx.x, tid = threadIdx.x;
  const int* off; const int* srow; const u32* x; u32* ag; int wid;
  if (bid < MBLK) {
    off = off_um; srow = srow_um; x = (const u32*)h_u; ag = (u32*)aggb_m;
    wid = (bid * 256 + tid) >> 6;
  } else {
    off = off_mu; srow = srow_mu; x = (const u32*)h_m; ag = (u32*)aggb_u;
    wid = ((bid - MBLK) * 256 + tid) >> 6;
  }
  int l = tid & 63, g = l >> 4, lr = l & 15;
  int s = off[wid], t = off[wid + 1];
  float a[8] = {};
  int j = s;
  for (; j + 16 <= t; j += 16) {
    int r0 = srow[j + g], r1 = srow[j + 4 + g];
    int r2 = srow[j + 8 + g], r3 = srow[j + 12 + g];
    u32x4 v0 = *(const u32x4*)(x + (size_t)r0 * 64 + lr * 4);
    u32x4 v1 = *(const u32x4*)(x + (size_t)r1 * 64 + lr * 4);
    u32x4 v2 = *(const u32x4*)(x + (size_t)r2 * 64 + lr * 4);
    u32x4 v3 = *(const u32x4*)(x + (size_t)r3 * 64 + lr * 4);
    #pragma unroll
    for (int k = 0; k < 4; ++k) {
      a[2 * k] += (bflo(v0[k]) + bflo(v1[k])) + (bflo(v2[k]) + bflo(v3[k]));
      a[2 * k + 1] += (bfhi(v0[k]) + bfhi(v1[k])) + (bfhi(v2[k]) + bfhi(v3[k]));
    }
  }
  for (; j + 4 <= t; j += 4) {
    int r0 = srow[j + g];
    u32x4 v0 = *(const u32x4*)(x + (size_t)r0 * 64 + lr * 4);
    #pragma unroll
    for (int k = 0; k < 4; ++k) { a[2 * k] += bflo(v0[k]); a[2 * k + 1] += bfhi(v0[k]); }
  }
  if (g < t - j) {
    int r0 = srow[j + g];
    u32x4 v0 = *(const u32x4*)(x + (size_t)r0 * 64 + lr * 4);
    #pragma unroll
    for (int k = 0; k < 4; ++k) { a[2 * k] += bflo(v0[k]); a[2 * k + 1] += bfhi(v0[k]); }
  }
  #pragma unroll
  for (int k = 0; k < 8; ++k) {
    a[k] += __shfl_xor(a[k], 16);
    a[k] += __shfl_xor(a[k], 32);
  }
  if (g == 0) {
    float inv = 1.f / (float)max(t - s, 1);
    u32x4 o;
    #pragma unroll
    for (int k = 0; k < 4; ++k)
      o[k] = (u32)bf16r(a[2 * k] * inv) | ((u32)bf16r(a[2 * k + 1] * inv) << 16);
    *(u32x4*)(ag + (size_t)wid * 64 + lr * 4) = o;
  }
}

// ---------------- merged layer-2 GEMM (bf16 MFMA): outb = bf16(aggb@Wtl + hb@Wtr + bias) ----
__global__ __launch_bounds__(256) void k_gemm2_mfma(
    const u16* __restrict__ aggb_m, const u16* __restrict__ h_m,
    const u16* __restrict__ WtA_m, const u16* __restrict__ WtB_m,
    const float* __restrict__ bias_m, u16* __restrict__ pm_b,
    const u16* __restrict__ aggb_u, const u16* __restrict__ h_u,
    const u16* __restrict__ WtA_u, const u16* __restrict__ WtB_u,
    const float* __restrict__ bias_u, u16* __restrict__ pu_b) {
  __shared__ u16 Zs[64 * 256];  // 32KB
  int tid = threadIdx.x;
  int bid = blockIdx.x;
  const u16 *aggb, *hb, *Wtl, *Wtr; const float* bias; u16* zb; int nd, r0;
  if (bid < G2MB) {
    aggb = aggb_m; hb = h_m; Wtl = WtA_m; Wtr = WtB_m; bias = bias_m; zb = pm_b;
    nd = NMV; r0 = bid * 64;
  } else {
    aggb = aggb_u; hb = h_u; Wtl = WtA_u; Wtr = WtB_u; bias = bias_u; zb = pu_b;
    nd = NUV; r0 = (bid - G2MB) * 64;
  }
  {
    int half = (tid >> 4) & 1;
    const u16* tab = half ? hb : aggb;
    #pragma unroll
    for (int it = 0; it < 8; ++it) {
      int q = tid + it * 256;
      int rl = q >> 5;
      int cc = (q & 15) ^ (rl & 7);
      int r = r0 + rl; r = r < nd ? r : nd - 1;
      const u16* src = tab + (size_t)r * 128 + cc * 8;
      u16* dst = Zs + (tid >> 6) * 512 + it * 2048;
      GLOAD_LDS16(src, dst);
    }
  }
  __syncthreads();
  int l = tid & 63, wv = tid >> 6;
  int lg = l >> 4, lr = l & 15;
  f32x4 acc[4][2];
  #pragma unroll
  for (int mt = 0; mt < 4; ++mt)
    #pragma unroll
    for (int c = 0; c < 2; ++c) acc[mt][c] = (f32x4){0.f, 0.f, 0.f, 0.f};
  #pragma unroll
  for (int cti = 0; cti < 2; ++cti) {
    int o = (wv * 2 + cti) * 16 + lr;
    const u16* wpl = Wtl + (size_t)o * 128 + lg * 8;
    const u16* wpr = Wtr + (size_t)o * 128 + lg * 8;
    s16x8 b[8];
    #pragma unroll
    for (int ks = 0; ks < 4; ++ks) b[ks] = *(const s16x8*)(wpl + ks * 32);
    #pragma unroll
    for (int ks = 0; ks < 4; ++ks) b[ks + 4] = *(const s16x8*)(wpr + ks * 32);
    #pragma unroll
    for (int mt = 0; mt < 4; ++mt) {
      int rl = mt * 16 + lr;
      int rb = rl * 512, sw = (rl & 7) << 4;
      #pragma unroll
      for (int ks = 0; ks < 8; ++ks) {
        s16x8 a = *(const s16x8*)((const char*)Zs + ((rb + ks * 64 + lg * 16) ^ sw));
        acc[mt][cti] = __builtin_amdgcn_mfma_f32_16x16x32_bf16(a, b[ks], acc[mt][cti], 0, 0, 0);
      }
    }
  }
  float bv[2];
  #pragma unroll
  for (int cti = 0; cti < 2; ++cti) bv[cti] = bias[(wv * 2 + cti) * 16 + lr];
  #pragma unroll
  for (int mt = 0; mt < 4; ++mt)
    #pragma unroll
    for (int cti = 0; cti < 2; ++cti) {
      int o = (wv * 2 + cti) * 16 + lr;
      #pragma unroll
      for (int rg = 0; rg < 4; ++rg) {
        int r = r0 + mt * 16 + lg * 4 + rg;
        if (r < nd) zb[(size_t)r * 128 + o] = bf16r(acc[mt][cti][rg] + bv[cti]);
      }
    }
}

// ---------------- edge op: out[e] = Wc2 . relu(pu[row_t[e]] + pm[col_t[e]]) + bc2 ----------------
__global__ __launch_bounds__(256) void k_edge(
    const u32* __restrict__ pu, const u32* __restrict__ pm,
    const int* __restrict__ row_t, const int* __restrict__ col_t,
    const float* __restrict__ Wc2, const float* __restrict__ bc2,
    float* __restrict__ out) {
  __shared__ float res[256];
  int tid = threadIdx.x, l = tid & 63, wv = tid >> 6;
  int lr = l & 15, g = l >> 4;
  float w2v[8];
  #pragma unroll
  for (int q = 0; q < 8; ++q) w2v[q] = Wc2[lr * 8 + q];
  int base = blockIdx.x * 256 + wv * 64;
  #pragma unroll 2
  for (int it = 0; it < 16; ++it) {
    int e = base + it * 4 + g;
    int ec = e < ETV ? e : ETV - 1;
    int r = row_t[ec], c = col_t[ec];
    u32x4 a = *(const u32x4*)(pu + (size_t)r * 64 + lr * 4);
    u32x4 b = *(const u32x4*)(pm + (size_t)c * 64 + lr * 4);
    float p = 0.f;
    #pragma unroll
    for (int q = 0; q < 4; ++q) {
      float h0 = bflo(a[q]) + bflo(b[q]);
      float h1 = bfhi(a[q]) + bfhi(b[q]);
      h0 = h0 > 0.f ? h0 : 0.f;
      h1 = h1 > 0.f ? h1 : 0.f;
      p += h0 * w2v[2 * q] + h1 * w2v[2 * q + 1];
    }
    p += __shfl_xor(p, 1); p += __shfl_xor(p, 2);
    p += __shfl_xor(p, 4); p += __shfl_xor(p, 8);
    if (lr == 0) res[wv * 64 + it * 4 + g] = p;
  }
  __syncthreads();
  int eo = blockIdx.x * 256 + tid;
  if (eo < ETV) out[eo] = res[tid] + bc2[0];
}

extern "C" void kernel_launch(void* const* d_in, const int* in_sizes, int n_in,
                              void* d_out, int out_size, void* d_ws, size_t ws_size,
                              hipStream_t stream) {
  const float* x_user  = (const float*)d_in[0];
  const float* x_merch = (const float*)d_in[1];
  const int* row_um = (const int*)d_in[2]; const int* col_um = (const int*)d_in[3];
  const int* row_mu = (const int*)d_in[4]; const int* col_mu = (const int*)d_in[5];
  const int* row_t  = (const int*)d_in[6]; const int* col_t  = (const int*)d_in[7];
  const float* W1l_um = (const float*)d_in[8];  const float* W1r_um = (const float*)d_in[9];  const float* b1_um = (const float*)d_in[10];
  const float* W1l_mu = (const float*)d_in[11]; const float* W1r_mu = (const float*)d_in[12]; const float* b1_mu = (const float*)d_in[13];
  const float* W2l_um = (const float*)d_in[14]; const float* W2r_um = (const float*)d_in[15]; const float* b2_um = (const float*)d_in[16];
  const float* W2l_mu = (const float*)d_in[17]; const float* W2r_mu = (const float*)d_in[18]; const float* b2_mu = (const float*)d_in[19];
  const float* Wc1 = (const float*)d_in[20]; const float* bc1 = (const float*)d_in[21];
  const float* Wc2 = (const float*)d_in[22]; const float* bc2 = (const float*)d_in[23];
  float* out = (float*)d_out;

  char* ws = (char*)d_ws;
  size_t p = 0;
  auto alloc = [&](size_t bytes) -> char* {
    char* r = ws + p;
    p = (p + bytes + 255) & ~(size_t)255;
    return r;
  };
  u32* cnt_um = (u32*)alloc((size_t)NCH * WNM * 4);     // per-chunk byte counters
  u32* cnt_mu = (u32*)alloc((size_t)NCH * WNU * 4);
  u32* pre_um = (u32*)alloc((size_t)NCH * WNM * 4);     // per-chunk byte prefixes
  u32* pre_mu = (u32*)alloc((size_t)NCH * WNU * 4);
  u32* rankp_um = (u32*)alloc((size_t)(NEV / 4) * 4);   // packed chunk-local ranks
  u32* rankp_mu = (u32*)alloc((size_t)(NEV / 4) * 4);
  int* off_um = (int*)alloc((size_t)(NMV + 4) * 4);
  int* off_mu = (int*)alloc((size_t)(NUV + 4) * 4);
  int* T    = (int*)alloc((size_t)(NMV + NUV) * 4);
  int* bsum = (int*)alloc((size_t)(NCA + NCB) * 4);
  int* srow_um = (int*)alloc((size_t)NEV * 4);
  int* srow_mu = (int*)alloc((size_t)NEV * 4);
  u16* cat_m = (u16*)alloc((size_t)NMV * 128 * 2);       // [agg64|xm32|pad32] bf16
  u16* cat_u = (u16*)alloc((size_t)NUV * 128 * 2);       // [agg32|xu64|pad32] bf16
  u16* h_m   = (u16*)alloc((size_t)NMV * 128 * 2);       // bf16 hidden
  u16* h_u   = (u16*)alloc((size_t)NUV * 128 * 2);
  u16* aggb_m = (u16*)alloc((size_t)NMV * 128 * 2);      // layer2 agg (bf16)
  u16* aggb_u = (u16*)alloc((size_t)NUV * 128 * 2);
  u16* pm_b  = (u16*)alloc((size_t)NMV * 128 * 2);       // folded classifier projections (bf16)
  u16* pu_b  = (u16*)alloc((size_t)NUV * 128 * 2);
  u16* WtA_u = (u16*)alloc((size_t)128 * 128 * 2);
  u16* WtB_u = (u16*)alloc((size_t)128 * 128 * 2);
  u16* WtA_m = (u16*)alloc((size_t)128 * 128 * 2);
  u16* WtB_m = (u16*)alloc((size_t)128 * 128 * 2);
  u16* Wt1_m = (u16*)alloc((size_t)128 * 128 * 2);
  u16* Wt1_u = (u16*)alloc((size_t)128 * 128 * 2);
  float* bias_u = (float*)alloc(128 * 4);
  float* bias_m = (float*)alloc(128 * 4);
  if (p > ws_size) return;  // workspace too small: fail loudly via absmax

  // merged prep (weights + cat x-region fill)
  k_prep<<<PWB + (NUV * 12 + NMV * 8 + 255) / 256, 256, 0, stream>>>(
      x_user, x_merch, W1l_um, W1r_um, W1l_mu, W1r_mu,
      W2l_um, W2r_um, W2l_mu, W2r_mu, b2_um, b2_mu, Wc1, bc1,
      WtA_u, WtB_u, WtA_m, WtB_m, Wt1_m, Wt1_u, bias_u, bias_m,
      (u32*)cat_u, (u32*)cat_m);
  // CSR build: LDS histogram (0 global atomics), byte prefix planes, off scan, scatter
  k_hist_lds<<<2 * NCH, 512, 0, stream>>>(col_um, rankp_um, cnt_um,
                                          col_mu, rankp_mu, cnt_mu);
  k_scan_s1<<<NCA + NCB, 1024, 0, stream>>>(cnt_um, pre_um, cnt_mu, pre_mu, T, bsum);
  k_scan_s3<<<NCA + NCB, 1024, 0, stream>>>(off_um, off_mu, T, bsum);
  k_scatter3<<<HGRID, 256, 0, stream>>>(col_um, row_um, rankp_um, pre_um, off_um, srow_um,
                                        col_mu, row_mu, rankp_mu, pre_mu, off_mu, srow_mu);
  // layer 1: deep-ILP bf16 gathers into cat agg-columns, then MFMA GEMM -> h
  k_agg_l1<<<MBLK + NUV / 4, 256, 0, stream>>>(off_um, srow_um, off_mu, srow_mu,
                                               (u32*)cat_u, (u32*)cat_m);
  k_gemm1_mfma<<<G1TM + (NUV + 63) / 64, 256, 0, stream>>>(cat_m, Wt1_m, b1_um, h_m,
                                                           cat_u, Wt1_u, b1_mu, h_u);
  // layer 2: deep-ILP bf16 gathers -> MFMA GEMM with folded classifier weights
  k_agg_l2<<<MBLK + NUV / 4, 256, 0, stream>>>(off_um, srow_um, h_u, aggb_m,
                                               off_mu, srow_mu, h_m, aggb_u);
  k_gemm2_mfma<<<G2MB + (NUV + 63) / 64, 256, 0, stream>>>(
      aggb_m, h_m, WtA_m, WtB_m, bias_m, pm_b,
      aggb_u, h_u, WtA_u, WtB_u, bias_u, pu_b);
  // edge classifier: gather + relu + dot
  k_edge<<<(ETV + 255) / 256, 256, 0, stream>>>((const u32*)pu_b, (const u32*)pm_b,
                                                row_t, col_t, Wc2, bc2, out);
}